// Round 5
// baseline (348.154 us; speedup 1.0000x reference)
//
#include <hip/hip_runtime.h>
#include <stdint.h>

typedef __bf16 bf16;
typedef __bf16 v8bf __attribute__((ext_vector_type(8)));
typedef __bf16 v4bf __attribute__((ext_vector_type(4)));
typedef float f32x4 __attribute__((ext_vector_type(4)));

#define MFMA16x16x32(a, b, c) __builtin_amdgcn_mfma_f32_16x16x32_bf16((a), (b), (c), 0, 0, 0)

__device__ __forceinline__ void async_ld16(const float* g, float* l) {
  __builtin_amdgcn_global_load_lds(
      (const __attribute__((address_space(1))) uint32_t*)g,
      (__attribute__((address_space(3))) uint32_t*)l, 16, 0, 0);
}

// ---------------- prep kernels ----------------
// Natural K layout: Wt[o][k], k<128 = h-channels 0..127, k>=128 = v.
__global__ __launch_bounds__(64) void prep_wt(const float* __restrict__ wfuse,
                                              const float* __restrict__ whpw,
                                              const float* __restrict__ wvpw,
                                              bf16* __restrict__ Wt) {
  int id = blockIdx.x * 64 + threadIdx.x;  // 32768 total
  int o = id >> 8, k = id & 255, ki = k & 127;
  const float* fr = wfuse + o * 256 + (k < 128 ? 0 : 128);
  const float* pw = (k < 128) ? whpw : wvpw;
  float a0 = 0.f, a1 = 0.f, a2 = 0.f, a3 = 0.f;
#pragma unroll 8
  for (int j = 0; j < 128; j += 4) {
    a0 = fmaf(fr[j + 0], pw[(j + 0) * 128 + ki], a0);
    a1 = fmaf(fr[j + 1], pw[(j + 1) * 128 + ki], a1);
    a2 = fmaf(fr[j + 2], pw[(j + 2) * 128 + ki], a2);
    a3 = fmaf(fr[j + 3], pw[(j + 3) * 128 + ki], a3);
  }
  Wt[o * 256 + k] = (bf16)((a0 + a1) + (a2 + a3));
}

__global__ void prep_dm(const float* __restrict__ wdm1,
                        const float* __restrict__ wdm2,
                        bf16* __restrict__ W1, bf16* __restrict__ W2) {
  int id = blockIdx.x * 256 + threadIdx.x;  // 8192
  if (id < 4096) W1[id] = (bf16)wdm1[id];
  else           W2[id - 4096] = (bf16)wdm2[id - 4096];
}

// ---------------- fused main kernel ----------------
// 1024 blocks = (b:2)x(hi:64)x(wchunk:8); tile 5 rows x 40 cols = 200 pos.
// Stencil is reorganized as Toeplitz 5->5 tasks: 1280 tasks/kk (2 orient x
// 16 ch x 40 runs), 2.5 per thread; each reads its 5-float run ONCE and
// writes 5 bf16 outputs to st[orient][pos][ch]. MFMA B-frag = 1 ds_read_b128.
// Pipeline per kk: stage(kk+2) | stencil(kk+1)->st[~] | MFMA(kk)<-st[kk&1],
// one barrier per kk (DMA gets a full iteration of flight).
// launch_bounds (512,4): 128 unified regs/wave; do NOT request 8 waves/EU
// (forces 64-reg budget -> acc spills -> 3x slowdown, measured r1).
__global__ __launch_bounds__(512, 4) void fused_main(
    const float* __restrict__ x,
    const float* __restrict__ whdw,   // [128][5]
    const float* __restrict__ wvdw,   // [128][5]
    const bf16* __restrict__ Wt,      // [128][256] natural K layout
    const bf16* __restrict__ W1,      // [32][128]
    const bf16* __restrict__ W2,      // [128][32]
    const float* __restrict__ scalep,
    float* __restrict__ out) {
  __shared__ __align__(16) char smemc[81920];
  float* xs0 = (float*)smemc;                    // [16][204] f32 (13056 B)
  float* xs1 = (float*)(smemc + 13056);          // [16][204]
  char* st0c = smemc + 26112;                    // [2][208][16] bf16 (13312 B)
  char* st1c = smemc + 39424;                    // [2][208][16] bf16
  float* whs = (float*)(smemc + 52736);          // [128][8]
  float* wvs = (float*)(smemc + 56832);          // [128][8]

  const int tid = threadIdx.x;
  const int w = tid >> 6, lane = tid & 63, ln16 = lane & 15, q = lane >> 4;
  const int hv = q >> 1;          // MFMA role: 0 = h k-half, 1 = v k-half
  const bool has1 = (w <= 4);     // s=1 tile (w+8) valid only if <=12

  const int bx = blockIdx.x;
  const int wc = bx & 7, hi = (bx >> 3) & 63, b = bx >> 9;
  const size_t xbase = (size_t)b * 13107200 + (size_t)(hi * 5) * 320 + (size_t)(wc * 40);
  const float* gx = x + xbase;

  // stage dw weights [128][8] rows (taps 0..4 used; 5..7 never read)
  for (int i = tid; i < 1280; i += 512) {
    int j = (i < 640) ? i : (i - 640);
    int c = j / 5, t = j - c * 5;
    float v = (i < 640) ? whdw[j] : wvdw[j];
    ((i < 640) ? whs : wvs)[c * 8 + t] = v;
  }
  // zero st pad positions 200..207 (both orients, both buffers, 16 ch)
  if (tid < 256) {
    int bsel = tid >> 7, rem = tid & 127;
    int orient = rem >> 6, rr = rem & 63;
    int pos = 200 + (rr >> 3), chp = rr & 7;
    *(uint32_t*)((bsel ? st1c : st0c) + orient * 6656 + pos * 32 + chp * 4) = 0u;
  }

  // ---- per-thread stencil task descriptors (kk-independent) ----
  // task T in [0,1280): orient = T>=640; r = T - 640*orient;
  // ch = r&15; tI = r>>4; h: run = (a = tI>>3, j = tI&7) base = a*40+5j;
  // v: base = col = tI. Outputs land at pos base + i*(h?1:40).
  int xidx0, stf0, ch0, hvt0;
  int xidx1, stf1, ch1, hvt1;
  int xidx2, stf2, ch2, hvt2;
  {
    int T = tid;  // 0..511: always h
    int c = T & 15, tI = T >> 4;
    int base = (tI >> 3) * 40 + (tI & 7) * 5;
    xidx0 = c * 204 + base; stf0 = base * 32 + c * 2; ch0 = c; hvt0 = 0;
  }
  {
    int T = tid + 512;  // 512..1023
    int iv = (T >= 640) ? 1 : 0;
    int r = T - (iv ? 640 : 0);
    int c = r & 15, tI = r >> 4;
    int base = iv ? tI : ((tI >> 3) * 40 + (tI & 7) * 5);
    xidx1 = c * 204 + base; stf1 = iv * 6656 + base * 32 + c * 2; ch1 = c; hvt1 = iv;
  }
  {
    int T = tid + 1024;  // 1024..1279 (tid<256): always v
    int r = T - 640;
    int c = r & 15, tI = r >> 4;
    xidx2 = c * 204 + tI; stf2 = 6656 + tI * 32 + c * 2; ch2 = c; hvt2 = 1;
  }

  // B-frag byte offsets into st buffer (s = 0, 1)
  const int boff0 = hv * 6656 + (w * 16 + ln16) * 32 + (q & 1) * 16;
  const int boff1 = hv * 6656 + ((w + 8) * 16 + ln16) * 32 + (q & 1) * 16;

  // 5->5 Toeplitz task: read run, 19 FMA (order-exact vs clamped-zero taps),
  // lrelu, write 5 bf16 to st.
  auto run_task = [&](const float* xb, char* stb, int c0,
                      int xidx, int stoff, int ch, int ishv) {
    const float* wrow = (ishv ? wvs : whs) + (c0 + ch) * 8;
    const float4 wv = *(const float4*)wrow;
    const float w4 = wrow[4];
    const float* xq = xb + xidx;
    float x0, x1, x2, x3, x4;
    if (ishv) { x0 = xq[0]; x1 = xq[40]; x2 = xq[80]; x3 = xq[120]; x4 = xq[160]; }
    else      { x0 = xq[0]; x1 = xq[1];  x2 = xq[2];  x3 = xq[3];   x4 = xq[4]; }
    float o0 = fmaf(w4, x2, fmaf(wv.w, x1, wv.z * x0));
    float o1 = fmaf(w4, x3, fmaf(wv.w, x2, fmaf(wv.z, x1, wv.y * x0)));
    float o2 = fmaf(w4, x4, fmaf(wv.w, x3, fmaf(wv.z, x2, fmaf(wv.y, x1, wv.x * x0))));
    float o3 = fmaf(wv.w, x4, fmaf(wv.z, x3, fmaf(wv.y, x2, wv.x * x1)));
    float o4 = fmaf(wv.z, x4, fmaf(wv.y, x3, wv.x * x2));
    auto lr = [](float v) { return fmaxf(v, 0.f) + 0.1f * fminf(v, 0.f); };
    bf16* sp = (bf16*)(stb + stoff);
    if (ishv) {
      sp[0]    = (bf16)lr(o0); sp[640]  = (bf16)lr(o1); sp[1280] = (bf16)lr(o2);
      sp[1920] = (bf16)lr(o3); sp[2560] = (bf16)lr(o4);
    } else {
      sp[0]  = (bf16)lr(o0); sp[16] = (bf16)lr(o1); sp[32] = (bf16)lr(o2);
      sp[48] = (bf16)lr(o3); sp[64] = (bf16)lr(o4);
    }
  };

  auto do_stencil = [&](int c0, const float* xb, char* stb) {
    run_task(xb, stb, c0, xidx0, stf0, ch0, hvt0);
    run_task(xb, stb, c0, xidx1, stf1, ch1, hvt1);
    if (tid < 256) run_task(xb, stb, c0, xidx2, stf2, ch2, hvt2);
  };

  // async stage of one 16-channel x chunk: wave w loads channels w and w+8;
  // 50 16B-slots per channel (lanes 0..49), LDS base wave-uniform.
  auto stage = [&](int kk, float* buf) {
    const int c0k = kk * 16;
#pragma unroll
    for (int h2 = 0; h2 < 2; ++h2) {
      const int c = w + 8 * h2;
      const float* gc = gx + (size_t)(c0k + c) * 102400;
      float* lb = buf + c * 204;
      if (lane < 50) {
        int r = lane / 10, c4 = lane - r * 10;
        async_ld16(gc + r * 320 + c4 * 4, lb);
      }
    }
  };

  f32x4 acc[2][8];
#pragma unroll
  for (int s = 0; s < 2; ++s)
#pragma unroll
    for (int m = 0; m < 8; ++m) acc[s][m] = (f32x4){0.f, 0.f, 0.f, 0.f};

  // prologue: stage tiles 0,1; publish weights+zeros+DMA; stencil tile 0
  stage(0, xs0);
  stage(1, xs1);
  __syncthreads();
  do_stencil(0, xs0, st0c);
  __syncthreads();

  for (int kk = 0; kk < 8; ++kk) {
    // DMA for tile kk+2 into xs[kk&1] (its readers finished last iter)
    if (kk < 6) stage(kk + 2, (kk & 1) ? xs1 : xs0);
    // stencil for tile kk+1: xs[(kk+1)&1] -> st[(kk+1)&1]
    if (kk < 7) do_stencil((kk + 1) * 16, (kk & 1) ? xs0 : xs1,
                           (kk & 1) ? st0c : st1c);
    // MFMA consume tile kk from st[kk&1] (published by last barrier)
    const char* stc = (kk & 1) ? st1c : st0c;
    v8bf b0 = *(const v8bf*)(stc + boff0);
    v8bf b1 = *(const v8bf*)(stc + boff1);  // garbage for w>4, MFMA skipped
    const int koff = kk * 16 + (q & 1) * 8 + hv * 128;
    v8bf af[8];
#pragma unroll
    for (int m = 0; m < 8; ++m)
      af[m] = *(const v8bf*)(Wt + (m * 16 + ln16) * 256 + koff);
#pragma unroll
    for (int m = 0; m < 8; ++m)
      acc[0][m] = MFMA16x16x32(af[m], b0, acc[0][m]);
    if (has1) {
#pragma unroll
      for (int m = 0; m < 8; ++m)
        acc[1][m] = MFMA16x16x32(af[m], b1, acc[1][m]);
    }
    __syncthreads();  // publish st[(kk+1)&1]; drain DMA(kk+2); close readers
  }

  // ---- epilogue (identical to r4, which passed) ----
  // Per-wave private 10240 B region: es(bf16) -> ts -> con(f32) overlays,
  // strictly sequential within the wave; no cross-wave traffic.
  char* wreg = smemc + w * 10240;
  bf16* es = (bf16*)wreg;            // [16 pos][144] bf16, XOR-swz (4608 B)
  bf16* ts = es;                     // [16 pos][40] overlay
  float* con = (float*)wreg;         // [128 o][20 pos] f32 overlay (10240 B)
  const float scl = scalep[0];
#define ESI(row, colv) ((row) * 144 + ((colv) ^ (((row) & 7) << 3)))

#pragma unroll
  for (int s = 0; s < 2; ++s) {
    const int nt = w + 8 * s;
    if (nt <= 12) {
      // 1) epi C-frags -> es[pos][o] bf16 (MFMA B-frag for depth-mlp)
#pragma unroll
      for (int m = 0; m < 8; ++m) {
        v4bf v;
        v[0] = (bf16)acc[s][m][0];
        v[1] = (bf16)acc[s][m][1];
        v[2] = (bf16)acc[s][m][2];
        v[3] = (bf16)acc[s][m][3];
        *(v4bf*)(es + ESI(ln16, m * 16 + q * 4)) = v;
      }
      // 2) t = lrelu(Wdm1 @ epi): M=32 (2 tiles), K=128 (4 steps)
      f32x4 tacc[2];
      tacc[0] = (f32x4){0.f, 0.f, 0.f, 0.f};
      tacc[1] = (f32x4){0.f, 0.f, 0.f, 0.f};
#pragma unroll
      for (int ks = 0; ks < 4; ++ks) {
        v8bf bfr = *(const v8bf*)(es + ESI(ln16, ks * 32 + q * 8));
#pragma unroll
        for (int m2 = 0; m2 < 2; ++m2) {
          v8bf afr = *(const v8bf*)(W1 + (m2 * 16 + ln16) * 128 + ks * 32 + q * 8);
          tacc[m2] = MFMA16x16x32(afr, bfr, tacc[m2]);
        }
      }
      // 3) lrelu(t) -> ts[pos][d] bf16
#pragma unroll
      for (int m2 = 0; m2 < 2; ++m2) {
        v4bf v;
#pragma unroll
        for (int r = 0; r < 4; ++r) {
          float tv = tacc[m2][r];
          tv = fmaxf(tv, 0.f) + 0.1f * fminf(tv, 0.f);
          v[r] = (bf16)tv;
        }
        *(v4bf*)(ts + ln16 * 40 + m2 * 16 + q * 4) = v;
      }
      // 4) dw = Wdm2 @ t; contrib = scl*epi*sigmoid(dw) -> con[o][pos] f32
      v8bf tb = *(const v8bf*)(ts + ln16 * 40 + q * 8);
#pragma unroll
      for (int m = 0; m < 8; ++m) {
        v8bf afr2 = *(const v8bf*)(W2 + (m * 16 + ln16) * 32 + q * 8);
        f32x4 z = {0.f, 0.f, 0.f, 0.f};
        f32x4 dacc = MFMA16x16x32(afr2, tb, z);
#pragma unroll
        for (int r = 0; r < 4; ++r) {
          const float sig = 1.0f / (1.0f + __expf(-dacc[r]));
          con[(m * 16 + q * 4 + r) * 20 + ln16] = scl * acc[s][m][r] * sig;
        }
      }
      // 5) transposed read: lane -> (channel o, 4 consecutive positions);
      //    float4-coalesced global IO (8x fewer VMEM instructions).
      const int ol = lane >> 2;
      const int p4 = (lane & 3) * 4;
      const int pos = nt * 16 + p4;
      if (pos < 200) {  // whole float4 valid or wholly invalid (200%4==0)
        const int a = pos / 40, colp = pos - a * 40;
        const size_t rowoff = xbase + (size_t)(a * 320 + colp);
#pragma unroll
        for (int i = 0; i < 8; ++i) {
          const int oo = i * 16 + ol;
          const f32x4 c4 = *(const f32x4*)(con + oo * 20 + p4);
          const size_t g = rowoff + (size_t)oo * 102400;
          const float4 xv = *(const float4*)(x + g);
          float4 ov;
          ov.x = xv.x + c4[0];
          ov.y = xv.y + c4[1];
          ov.z = xv.z + c4[2];
          ov.w = xv.w + c4[3];
          *(float4*)(out + g) = ov;
        }
      }
    }
  }
#undef ESI
}

// ---------------- launcher ----------------
extern "C" void kernel_launch(void* const* d_in, const int* in_sizes, int n_in,
                              void* d_out, int out_size, void* d_ws, size_t ws_size,
                              hipStream_t stream) {
  (void)in_sizes; (void)n_in; (void)out_size; (void)ws_size;
  const float* x     = (const float*)d_in[0];
  const float* whdw  = (const float*)d_in[1];
  const float* whpw  = (const float*)d_in[2];
  const float* wvdw  = (const float*)d_in[3];
  const float* wvpw  = (const float*)d_in[4];
  const float* wdm1  = (const float*)d_in[5];
  const float* wdm2  = (const float*)d_in[6];
  const float* wfuse = (const float*)d_in[7];
  const float* scale = (const float*)d_in[8];

  bf16* Wt = (bf16*)d_ws;          // 128*256 bf16
  bf16* W1 = Wt + 32768;           // 32*128
  bf16* W2 = W1 + 4096;            // 128*32

  prep_wt<<<512, 64, 0, stream>>>(wfuse, whpw, wvpw, Wt);
  prep_dm<<<32, 256, 0, stream>>>(wdm1, wdm2, W1, W2);
  fused_main<<<1024, 512, 0, stream>>>(x, whdw, wvdw, Wt, W1, W2, scale, (float*)d_out);
}